// Round 15
// baseline (172.453 us; speedup 1.0000x reference)
//
#include <hip/hip_runtime.h>
#include <hip/hip_bf16.h>
#include <hip/hip_fp16.h>

#define N_NODES 50000
#define N_EDGES 800000
#define HID 128
#define NPROJ 391      // ceil(50000/128) projp tiles (128-row, proven)
#define CAP 48         // per-node bucket capacity (deg ~ Poisson(16))
#define NBIN 196       // bins of 256 nodes: bin = dst >> 8
#define BINSH 8
#define NCOARSE 98     // coarse blocks x 8192 edges >= 800,000
#define CAPBB 96       // per-(bin,block) slice cap (mean 41.9, sd 6.5 -> +8.3 sigma)
#define OVB 8192       // per-block overflow slice: worst case ALL edges -> exact

typedef __bf16 bf16x8 __attribute__((ext_vector_type(8)));
typedef float f32x4 __attribute__((ext_vector_type(4)));

// ---------------------------------------------------------------------------
// fused: 2-dispatch pipeline, kernel 1 of 2 (prep DELETED: binning needs no
// zero-init -- per-(bin,block) fixed slices + unconditional count writes;
// weights consumed raw-f32 with on-the-fly (__bf16) cast == prep's exact
// conversion, so MFMA inputs are bit-identical).
//   blocks [0,NCOARSE)             = coarse binning
//   blocks [NCOARSE,NCOARSE+NPROJ) = projp 128-row tiles
// ---------------------------------------------------------------------------
__global__ __launch_bounds__(256) void fused_kernel(
    const float* __restrict__ x, const float* __restrict__ Win,
    const float* __restrict__ W1, const float* __restrict__ b_in,
    const float* __restrict__ b1, __half* __restrict__ P1h,
    __bf16* __restrict__ P1b, const int* __restrict__ eidx,
    int* __restrict__ cnt2, unsigned int* __restrict__ binbuf,
    int* __restrict__ ovfb_cnt, unsigned int* __restrict__ ovfb)
{
    __shared__ __bf16 At[128][136];
    int bb = blockIdx.x;
    int tid = threadIdx.x;

    if (bb < NCOARSE) {
        // ---- coarse: bin 8192 edges into FIXED per-(bin,block) slices ----
        int* lcnt = (int*)&At[0][0];        // NBIN ints aliased
        int* oidx = lcnt + NBIN;            // 1 int aliased
        int e0 = bb * 8192;
        for (int i = tid; i < NBIN; i += 256) lcnt[i] = 0;
        if (tid == 0) *oidx = 0;
        __syncthreads();
        // pass 1: count
        for (int k = 0; k < 32; ++k) {
            int e = e0 + k * 256 + tid;
            if (e < N_EDGES)
                atomicAdd(&lcnt[eidx[N_EDGES + e] >> BINSH], 1);
        }
        __syncthreads();
        // write FULL counts unconditionally (no pre-zeroing needed anywhere)
        for (int i = tid; i < NBIN; i += 256) {
            cnt2[i * NCOARSE + bb] = lcnt[i];
            lcnt[i] = 0;
        }
        __syncthreads();
        // pass 2: scatter into block-private slice; extras -> exact ovfb
        for (int k = 0; k < 32; ++k) {
            int e = e0 + k * 256 + tid;
            if (e < N_EDGES) {
                int d = eidx[N_EDGES + e];
                int s = eidx[e];
                int b = d >> BINSH;
                int p = atomicAdd(&lcnt[b], 1);
                unsigned int u = ((unsigned)d << 16) | (unsigned)s;
                if (p < CAPBB) binbuf[(b * NCOARSE + bb) * CAPBB + p] = u;
                else { int o = atomicAdd(oidx, 1); ovfb[bb * OVB + o] = u; }
            }
        }
        __syncthreads();
        if (tid == 0) ovfb_cnt[bb] = *oidx;   // unconditional; <= OVB by constr.
        return;
    }

    // ---- projp: 128-row tile, 4 waves x 32 rows, raw-f32 B fragments ----
    int wave = tid >> 6, lane = tid & 63;
    int r_lane = lane & 15, quad = lane >> 4;
    int m0 = (bb - NCOARSE) * 128;

    for (int i = tid; i < 128 * 32; i += 256) {
        int r = i >> 5, c = i & 31;
        int row = m0 + r;
        float4 v = make_float4(0.f, 0.f, 0.f, 0.f);
        if (row < N_NODES) v = *(const float4*)(x + (long)row * HID + c * 4);
        __bf16* dst = &At[r][c * 4];
        dst[0] = (__bf16)v.x; dst[1] = (__bf16)v.y;
        dst[2] = (__bf16)v.z; dst[3] = (__bf16)v.w;
    }
    __syncthreads();

    // stage 1: h = relu(x @ W_in + b_in), in place
    {
        f32x4 acc[2][8] = {};
#pragma unroll
        for (int ks = 0; ks < 4; ++ks) {
            int krow = ks * 32 + quad * 8;
            bf16x8 bf[8];
#pragma unroll
            for (int n = 0; n < 8; ++n) {
                const float* wp = Win + (long)krow * HID + n * 16 + r_lane;
#pragma unroll
                for (int j = 0; j < 8; ++j)
                    bf[n][j] = (__bf16)wp[j * HID];
            }
            int kb = ks * 32 + quad * 8;
            bf16x8 a0 = *(const bf16x8*)(&At[wave * 32 + r_lane][kb]);
            bf16x8 a1 = *(const bf16x8*)(&At[wave * 32 + 16 + r_lane][kb]);
#pragma unroll
            for (int n = 0; n < 8; ++n) {
                acc[0][n] = __builtin_amdgcn_mfma_f32_16x16x32_bf16(a0, bf[n], acc[0][n], 0, 0, 0);
                acc[1][n] = __builtin_amdgcn_mfma_f32_16x16x32_bf16(a1, bf[n], acc[1][n], 0, 0, 0);
            }
        }
#pragma unroll
        for (int n = 0; n < 8; ++n) {
            int col = n * 16 + r_lane;
            float bias = b_in[col];
#pragma unroll
            for (int mt = 0; mt < 2; ++mt) {
                int rb = wave * 32 + mt * 16 + quad * 4;
#pragma unroll
                for (int r = 0; r < 4; ++r) {
                    float v = acc[mt][n][r] + bias;
                    At[rb + r][col] = (__bf16)(v > 0.f ? v : 0.f);
                }
            }
        }
    }
    __syncthreads();

    // stage 2a: P1h = (fp16)(h @ W1a + b1)
    {
        f32x4 acc[2][8] = {};
#pragma unroll
        for (int ks = 0; ks < 4; ++ks) {
            int krow = ks * 32 + quad * 8;
            bf16x8 bf[8];
#pragma unroll
            for (int n = 0; n < 8; ++n) {
                const float* wp = W1 + (long)krow * HID + n * 16 + r_lane;
#pragma unroll
                for (int j = 0; j < 8; ++j)
                    bf[n][j] = (__bf16)wp[j * HID];
            }
            int kb = ks * 32 + quad * 8;
            bf16x8 a0 = *(const bf16x8*)(&At[wave * 32 + r_lane][kb]);
            bf16x8 a1 = *(const bf16x8*)(&At[wave * 32 + 16 + r_lane][kb]);
#pragma unroll
            for (int n = 0; n < 8; ++n) {
                acc[0][n] = __builtin_amdgcn_mfma_f32_16x16x32_bf16(a0, bf[n], acc[0][n], 0, 0, 0);
                acc[1][n] = __builtin_amdgcn_mfma_f32_16x16x32_bf16(a1, bf[n], acc[1][n], 0, 0, 0);
            }
        }
#pragma unroll
        for (int n = 0; n < 8; ++n) {
            int col = n * 16 + r_lane;
            float bias = b1[col];
#pragma unroll
            for (int mt = 0; mt < 2; ++mt) {
                int rbase = m0 + wave * 32 + mt * 16 + quad * 4;
#pragma unroll
                for (int r = 0; r < 4; ++r) {
                    int row = rbase + r;
                    if (row < N_NODES)
                        P1h[(long)row * HID + col] = __float2half(acc[mt][n][r] + bias);
                }
            }
        }
    }

    // stage 2b: P1b = h @ W1b (bf16); W1b = W1 rows [128,256)
    {
        const float* W1b = W1 + (long)HID * HID;
        f32x4 acc[2][8] = {};
#pragma unroll
        for (int ks = 0; ks < 4; ++ks) {
            int krow = ks * 32 + quad * 8;
            bf16x8 bf[8];
#pragma unroll
            for (int n = 0; n < 8; ++n) {
                const float* wp = W1b + (long)krow * HID + n * 16 + r_lane;
#pragma unroll
                for (int j = 0; j < 8; ++j)
                    bf[n][j] = (__bf16)wp[j * HID];
            }
            int kb = ks * 32 + quad * 8;
            bf16x8 a0 = *(const bf16x8*)(&At[wave * 32 + r_lane][kb]);
            bf16x8 a1 = *(const bf16x8*)(&At[wave * 32 + 16 + r_lane][kb]);
#pragma unroll
            for (int n = 0; n < 8; ++n) {
                acc[0][n] = __builtin_amdgcn_mfma_f32_16x16x32_bf16(a0, bf[n], acc[0][n], 0, 0, 0);
                acc[1][n] = __builtin_amdgcn_mfma_f32_16x16x32_bf16(a1, bf[n], acc[1][n], 0, 0, 0);
            }
        }
#pragma unroll
        for (int n = 0; n < 8; ++n) {
            int col = n * 16 + r_lane;
#pragma unroll
            for (int mt = 0; mt < 2; ++mt) {
                int rbase = m0 + wave * 32 + mt * 16 + quad * 4;
#pragma unroll
                for (int r = 0; r < 4; ++r) {
                    int row = rbase + r;
                    if (row < N_NODES)
                        P1b[(long)row * HID + col] = (__bf16)acc[mt][n][r];
                }
            }
        }
    }
}

// ---------------------------------------------------------------------------
// 8 relu-accumulates of one P1b row (8 bf16 in uint4) against P1a (f32x8)
// ---------------------------------------------------------------------------
__device__ inline void acc8(float4& rA, float4& rB,
                            const float4 paA, const float4 paB, uint4 q)
{
    float t;
    t = paA.x + __uint_as_float(q.x << 16);         rA.x += t > 0.f ? t : 0.f;
    t = paA.y + __uint_as_float(q.x & 0xffff0000u); rA.y += t > 0.f ? t : 0.f;
    t = paA.z + __uint_as_float(q.y << 16);         rA.z += t > 0.f ? t : 0.f;
    t = paA.w + __uint_as_float(q.y & 0xffff0000u); rA.w += t > 0.f ? t : 0.f;
    t = paB.x + __uint_as_float(q.z << 16);         rB.x += t > 0.f ? t : 0.f;
    t = paB.y + __uint_as_float(q.z & 0xffff0000u); rB.y += t > 0.f ? t : 0.f;
    t = paB.z + __uint_as_float(q.w << 16);         rB.z += t > 0.f ? t : 0.f;
    t = paB.w + __uint_as_float(q.w & 0xffff0000u); rB.w += t > 0.f ? t : 0.f;
}

// ---------------------------------------------------------------------------
// aggnode (structure proven R13/R14): phase 0 scans its bin's 98 fixed
// slices (flattened, LDS-cached counts) + normally-empty ovfb drain;
// deg = lcur (coarse never drops edges). Phase 2 W2 decoded raw-f32.
// ---------------------------------------------------------------------------
__global__ __launch_bounds__(512) void aggnode_kernel(
    const __half* __restrict__ P1h, const __bf16* __restrict__ P1b,
    const unsigned int* __restrict__ binbuf, const int* __restrict__ cnt2,
    const int* __restrict__ ovfb_cnt, const unsigned int* __restrict__ ovfb,
    const float* __restrict__ W2, const float* __restrict__ b2,
    const float* __restrict__ Wc, const float* __restrict__ bc,
    float* __restrict__ out)
{
    __shared__ __bf16 At[128][136];
    __shared__ unsigned short idx[128][CAP];
    __shared__ int lcur[128];
    __shared__ int degS[128];
    __shared__ unsigned int lovf[128];
    __shared__ int lovf_cnt;
    __shared__ int cntS[NCOARSE];
    __shared__ int ovfS[NCOARSE];
    int tid = threadIdx.x;
    int blk = blockIdx.x;
    int m0 = blk * 128;
    int bin = blk >> 1;

    // ---- phase 0: scatter bin pairs into LDS buckets ----
    if (tid < 128) lcur[tid] = 0;
    if (tid == 0) lovf_cnt = 0;
    if (tid < NCOARSE) {
        int c = cnt2[bin * NCOARSE + tid];
        cntS[tid] = c > CAPBB ? CAPBB : c;
        ovfS[tid] = ovfb_cnt[tid];
    }
    __syncthreads();
    {
        const unsigned int* base = binbuf + (long)bin * NCOARSE * CAPBB;
        for (int i = tid; i < NCOARSE * CAPBB; i += 512) {
            int bb2 = i / CAPBB;
            int pos = i - bb2 * CAPBB;
            if (pos < cntS[bb2]) {
                unsigned int u = base[i];
                int d = (int)(u >> 16);
                if ((d >> 7) == blk) {          // our 128-node half of the bin
                    int p = atomicAdd(&lcur[d & 127], 1);
                    if (p < CAP) idx[d & 127][p] = (unsigned short)(u & 0xffffu);
                    else { int o = atomicAdd(&lovf_cnt, 1);
                           if (o < 128) lovf[o] = u; }
                }
            }
        }
        // exact drain of coarse slice-overflow (normally all counts are 0)
        for (int bb2 = 0; bb2 < NCOARSE; ++bb2) {
            int nv = ovfS[bb2];
            if (nv <= 0) continue;
            if (nv > OVB) nv = OVB;
            for (int i = tid; i < nv; i += 512) {
                unsigned int u = ovfb[bb2 * OVB + i];
                int d = (int)(u >> 16);
                if ((d >> 7) == blk) {
                    int p = atomicAdd(&lcur[d & 127], 1);
                    if (p < CAP) idx[d & 127][p] = (unsigned short)(u & 0xffffu);
                    else { int o = atomicAdd(&lovf_cnt, 1);
                           if (o < 128) lovf[o] = u; }
                }
            }
        }
    }
    __syncthreads();
    if (tid < 128) degS[tid] = lcur[tid];
    __syncthreads();
    int lc = lovf_cnt;
    if (lc > 128) lc = 128;

    // ---- phase 1: aggregate into At ----
    {
        int team = tid >> 4;        // 0..31
        int tl = tid & 15;          // cols [8tl, 8tl+8)
        for (int g = 0; g < 4; ++g) {
            int r = team * 4 + g;
            int node = m0 + r;
            float4 rA = make_float4(0.f, 0.f, 0.f, 0.f);
            float4 rB = make_float4(0.f, 0.f, 0.f, 0.f);
            if (node < N_NODES) {
                int deg = lcur[r];
                if (deg > CAP) deg = CAP;
                const unsigned short* ip = idx[r];
                uint4 ph = *(const uint4*)(P1h + (long)node * HID + tl * 8);
                float2 c0 = __half22float2(*(const __half2*)&ph.x);
                float2 c1 = __half22float2(*(const __half2*)&ph.y);
                float2 c2 = __half22float2(*(const __half2*)&ph.z);
                float2 c3 = __half22float2(*(const __half2*)&ph.w);
                float4 paA = make_float4(c0.x, c0.y, c1.x, c1.y);
                float4 paB = make_float4(c2.x, c2.y, c3.x, c3.y);
                int j = 0;
                for (; j + 8 <= deg; j += 8) {
                    int s0 = ip[j + 0];
                    int s1 = ip[j + 1];
                    int s2 = ip[j + 2];
                    int s3 = ip[j + 3];
                    int s4 = ip[j + 4];
                    int s5 = ip[j + 5];
                    int s6 = ip[j + 6];
                    int s7 = ip[j + 7];
                    uint4 q0 = *(const uint4*)(P1b + (long)s0 * HID + tl * 8);
                    uint4 q1 = *(const uint4*)(P1b + (long)s1 * HID + tl * 8);
                    uint4 q2 = *(const uint4*)(P1b + (long)s2 * HID + tl * 8);
                    uint4 q3 = *(const uint4*)(P1b + (long)s3 * HID + tl * 8);
                    uint4 q4 = *(const uint4*)(P1b + (long)s4 * HID + tl * 8);
                    uint4 q5 = *(const uint4*)(P1b + (long)s5 * HID + tl * 8);
                    uint4 q6 = *(const uint4*)(P1b + (long)s6 * HID + tl * 8);
                    uint4 q7 = *(const uint4*)(P1b + (long)s7 * HID + tl * 8);
                    acc8(rA, rB, paA, paB, q0);
                    acc8(rA, rB, paA, paB, q1);
                    acc8(rA, rB, paA, paB, q2);
                    acc8(rA, rB, paA, paB, q3);
                    acc8(rA, rB, paA, paB, q4);
                    acc8(rA, rB, paA, paB, q5);
                    acc8(rA, rB, paA, paB, q6);
                    acc8(rA, rB, paA, paB, q7);
                }
                for (; j < deg; ++j) {
                    int s = ip[j];
                    uint4 q = *(const uint4*)(P1b + (long)s * HID + tl * 8);
                    acc8(rA, rB, paA, paB, q);
                }
                for (int t = 0; t < lc; ++t) {   // in-block bucket overflow
                    unsigned int u = lovf[t];
                    if ((int)(u >> 16) == node) {
                        uint4 q = *(const uint4*)(P1b + (long)(u & 0xffffu) * HID + tl * 8);
                        acc8(rA, rB, paA, paB, q);
                    }
                }
            }
            __bf16 vv[8];
            vv[0] = (__bf16)rA.x; vv[1] = (__bf16)rA.y;
            vv[2] = (__bf16)rA.z; vv[3] = (__bf16)rA.w;
            vv[4] = (__bf16)rB.x; vv[5] = (__bf16)rB.y;
            vv[6] = (__bf16)rB.z; vv[7] = (__bf16)rB.w;
            *(uint4*)(&At[r][tl * 8]) = *(uint4*)vv;
        }
    }
    __syncthreads();

    // ---- phase 2: node GEMM, 8 waves x one 16-row m-tile (raw-f32 W2) ----
    int wave = tid >> 6, lane = tid & 63;
    int r_lane = lane & 15, quad = lane >> 4;
    f32x4 acc[8] = {};
#pragma unroll
    for (int ks = 0; ks < 4; ++ks) {
        int krow = ks * 32 + quad * 8;
        bf16x8 bf[8];
#pragma unroll
        for (int n = 0; n < 8; ++n) {
            const float* wp = W2 + (long)krow * HID + n * 16 + r_lane;
#pragma unroll
            for (int j = 0; j < 8; ++j)
                bf[n][j] = (__bf16)wp[j * HID];
        }
        int kb = ks * 32 + quad * 8;
        bf16x8 a0 = *(const bf16x8*)(&At[wave * 16 + r_lane][kb]);
#pragma unroll
        for (int n = 0; n < 8; ++n)
            acc[n] = __builtin_amdgcn_mfma_f32_16x16x32_bf16(a0, bf[n], acc[n], 0, 0, 0);
    }

#pragma unroll
    for (int r = 0; r < 4; ++r) {
        int lr = wave * 16 + quad * 4 + r;
        int row = m0 + lr;
        float deg = (float)degS[lr];
        float s0 = 0.f, s1 = 0.f;
#pragma unroll
        for (int n = 0; n < 8; ++n) {
            int col = n * 16 + r_lane;
            float v = acc[n][r] + deg * b2[col];
            v = v > 0.f ? v : 0.f;
            s0 += v * Wc[col * 2 + 0];
            s1 += v * Wc[col * 2 + 1];
        }
#pragma unroll
        for (int off = 1; off < 16; off <<= 1) {
            s0 += __shfl_xor(s0, off);
            s1 += __shfl_xor(s1, off);
        }
        if (r_lane == 0 && row < N_NODES) {
            out[(long)row * 2 + 0] = s0 + bc[0];
            out[(long)row * 2 + 1] = s1 + bc[1];
        }
    }
}

extern "C" void kernel_launch(void* const* d_in, const int* in_sizes, int n_in,
                              void* d_out, int out_size, void* d_ws, size_t ws_size,
                              hipStream_t stream) {
    const float* x    = (const float*)d_in[0];
    const int* eidx   = (const int*)d_in[1];
    const float* W_in = (const float*)d_in[2];
    const float* b_in = (const float*)d_in[3];
    const float* W1   = (const float*)d_in[4];
    const float* b1   = (const float*)d_in[5];
    const float* W2   = (const float*)d_in[6];
    const float* b2   = (const float*)d_in[7];
    const float* Wc   = (const float*)d_in[8];
    const float* bc   = (const float*)d_in[9];
    float* out = (float*)d_out;

    char* ws = (char*)d_ws;
    __half* P1h  = (__half*)(ws + 0);                       // 12,800,000
    __bf16* P1b  = (__bf16*)(ws + 12800000);                // 12,800,000 -> 25,600,000
    int* cnt2    = (int*)(ws + 25600000);                   // 196*98*4 = 76,832 -> 25,676,832
    int* ovfb_cnt= (int*)(ws + 25676832);                   // 98*4 = 392 -> 25,677,224 (pad)
    unsigned int* binbuf = (unsigned int*)(ws + 25677312);  // 196*98*96*4 = 7,375,872 -> 33,053,184
    unsigned int* ovfb   = (unsigned int*)(ws + 33053184);  // 98*8192*4 = 3,211,264 -> 36,264,448

    fused_kernel<<<NCOARSE + NPROJ, 256, 0, stream>>>(
        x, W_in, W1, b_in, b1, P1h, P1b, eidx, cnt2, binbuf, ovfb_cnt, ovfb);
    aggnode_kernel<<<(N_NODES + 127) / 128, 512, 0, stream>>>(
        P1h, P1b, binbuf, cnt2, ovfb_cnt, ovfb, W2, b2, Wc, bc, out);
}

// Round 16
// 160.285 us; speedup vs baseline: 1.0759x; 1.0759x over previous
//
#include <hip/hip_runtime.h>
#include <hip/hip_bf16.h>
#include <hip/hip_fp16.h>

#define N_NODES 50000
#define N_EDGES 800000
#define HID 128
#define NPROJ 391      // ceil(50000/128) projp tiles (128-row, R9-proven)
#define CAP 48         // per-node bucket capacity (deg ~ Poisson(16); overflow exact)
#define OVF_MAX 8192
#define NBIN 196       // bins of 256 nodes: bin = dst >> 8
#define BINSH 8
#define BINCAP 4608    // pairs per bin (mean 4082, sd 64; overflow exact)
#define NCOARSE 98     // coarse blocks x 8192 edges >= 800,000

typedef __bf16 bf16x8 __attribute__((ext_vector_type(8)));
typedef float f32x4 __attribute__((ext_vector_type(4)));

// ---------------------------------------------------------------------------
// prep: repack weights into MFMA-B-fragment-major bf16; zero cursor (50000)
// + bincnt (196) + ovf_cnt (1) -- contiguous ints.
// ---------------------------------------------------------------------------
__global__ __launch_bounds__(256) void prep_kernel(
    const float* __restrict__ Win, const float* __restrict__ W1,
    const float* __restrict__ W2, __bf16* __restrict__ Wsw,
    int* __restrict__ curz)
{
    int id = blockIdx.x * 256 + threadIdx.x;   // 0..65535
    int m     = id >> 14;
    int rem   = id & 16383;
    int j     = rem & 7;
    int lane  = (rem >> 3) & 63;
    int ntile = (rem >> 9) & 7;
    int kstep = rem >> 12;
    int k = kstep * 32 + (lane >> 4) * 8 + j;
    int n = ntile * 16 + (lane & 15);
    float v;
    if (m == 0)      v = Win[k * HID + n];
    else if (m == 1) v = W1[k * HID + n];
    else if (m == 2) v = W1[(k + HID) * HID + n];
    else             v = W2[k * HID + n];
    Wsw[id] = (__bf16)v;
    if (id < N_NODES + NBIN + 1) curz[id] = 0;   // cursor + bincnt + ovf_cnt
}

// ---------------------------------------------------------------------------
// fused (R13-proven bodies; R14: P1a stored as fp16):
//   blocks [0,NCOARSE)             = coarse binning
//   blocks [NCOARSE,NCOARSE+NPROJ) = projp 128-row tiles
// ---------------------------------------------------------------------------
__global__ __launch_bounds__(256) void fused_kernel(
    const float* __restrict__ x, const __bf16* __restrict__ Wsw,
    const float* __restrict__ b_in, const float* __restrict__ b1,
    __half* __restrict__ P1h, __bf16* __restrict__ P1b,
    const int* __restrict__ eidx, int* __restrict__ bincnt,
    unsigned int* __restrict__ binbuf, int* __restrict__ cursor,
    int* __restrict__ ovf_cnt, uint2* __restrict__ ovf)
{
    __shared__ __bf16 At[128][136];
    int bb = blockIdx.x;
    int tid = threadIdx.x;

    if (bb < NCOARSE) {
        // ---- coarse: bin 8192 edges by dst>>8 into block-private chunks ----
        int* lcnt  = (int*)&At[0][0];       // 2*NBIN ints aliased (1.6KB << 34.8KB)
        int* lbase = lcnt + NBIN;
        int e0 = bb * 8192;
        for (int i = tid; i < NBIN; i += 256) lcnt[i] = 0;
        __syncthreads();
        for (int k = 0; k < 32; ++k) {
            int e = e0 + k * 256 + tid;
            if (e < N_EDGES)
                atomicAdd(&lcnt[eidx[N_EDGES + e] >> BINSH], 1);
        }
        __syncthreads();
        for (int i = tid; i < NBIN; i += 256) {
            lbase[i] = atomicAdd(&bincnt[i], lcnt[i]);
            lcnt[i] = 0;
        }
        __syncthreads();
        for (int k = 0; k < 32; ++k) {
            int e = e0 + k * 256 + tid;
            if (e < N_EDGES) {
                int d = eidx[N_EDGES + e];
                int s = eidx[e];
                int b = d >> BINSH;
                int p = lbase[b] + atomicAdd(&lcnt[b], 1);
                if (p < BINCAP) {
                    binbuf[b * BINCAP + p] = ((unsigned)d << 16) | (unsigned)s;
                } else {            // exact overflow path (astronomically rare)
                    int o = atomicAdd(ovf_cnt, 1);
                    if (o < OVF_MAX) ovf[o] = make_uint2((unsigned)d, (unsigned)s);
                    atomicAdd(&cursor[d], 1);   // keep deg exact
                }
            }
        }
        return;
    }

    // ---- projp: 128-row tile, 4 waves x 32 rows, bf[8]-batched B loads ----
    int wave = tid >> 6, lane = tid & 63;
    int r_lane = lane & 15, quad = lane >> 4;
    int m0 = (bb - NCOARSE) * 128;

    for (int i = tid; i < 128 * 32; i += 256) {
        int r = i >> 5, c = i & 31;
        int row = m0 + r;
        float4 v = make_float4(0.f, 0.f, 0.f, 0.f);
        if (row < N_NODES) v = *(const float4*)(x + (long)row * HID + c * 4);
        __bf16* dst = &At[r][c * 4];
        dst[0] = (__bf16)v.x; dst[1] = (__bf16)v.y;
        dst[2] = (__bf16)v.z; dst[3] = (__bf16)v.w;
    }
    __syncthreads();

    // stage 1: h = relu(x @ W_in + b_in), in place
    {
        f32x4 acc[2][8] = {};
#pragma unroll
        for (int ks = 0; ks < 4; ++ks) {
            int kb = ks * 32 + quad * 8;
            bf16x8 bf[8];
#pragma unroll
            for (int n = 0; n < 8; ++n)
                bf[n] = *(const bf16x8*)(Wsw + ((ks * 8 + n) * 64 + lane) * 8);
            bf16x8 a0 = *(const bf16x8*)(&At[wave * 32 + r_lane][kb]);
            bf16x8 a1 = *(const bf16x8*)(&At[wave * 32 + 16 + r_lane][kb]);
#pragma unroll
            for (int n = 0; n < 8; ++n) {
                acc[0][n] = __builtin_amdgcn_mfma_f32_16x16x32_bf16(a0, bf[n], acc[0][n], 0, 0, 0);
                acc[1][n] = __builtin_amdgcn_mfma_f32_16x16x32_bf16(a1, bf[n], acc[1][n], 0, 0, 0);
            }
        }
#pragma unroll
        for (int n = 0; n < 8; ++n) {
            int col = n * 16 + r_lane;
            float bias = b_in[col];
#pragma unroll
            for (int mt = 0; mt < 2; ++mt) {
                int rb = wave * 32 + mt * 16 + quad * 4;
#pragma unroll
                for (int r = 0; r < 4; ++r) {
                    float v = acc[mt][n][r] + bias;
                    At[rb + r][col] = (__bf16)(v > 0.f ? v : 0.f);
                }
            }
        }
    }
    __syncthreads();

    // stage 2a: P1h = (fp16)(h @ W1a + b1)
    {
        const __bf16* W1a = Wsw + 16384;
        f32x4 acc[2][8] = {};
#pragma unroll
        for (int ks = 0; ks < 4; ++ks) {
            int kb = ks * 32 + quad * 8;
            bf16x8 bf[8];
#pragma unroll
            for (int n = 0; n < 8; ++n)
                bf[n] = *(const bf16x8*)(W1a + ((ks * 8 + n) * 64 + lane) * 8);
            bf16x8 a0 = *(const bf16x8*)(&At[wave * 32 + r_lane][kb]);
            bf16x8 a1 = *(const bf16x8*)(&At[wave * 32 + 16 + r_lane][kb]);
#pragma unroll
            for (int n = 0; n < 8; ++n) {
                acc[0][n] = __builtin_amdgcn_mfma_f32_16x16x32_bf16(a0, bf[n], acc[0][n], 0, 0, 0);
                acc[1][n] = __builtin_amdgcn_mfma_f32_16x16x32_bf16(a1, bf[n], acc[1][n], 0, 0, 0);
            }
        }
#pragma unroll
        for (int n = 0; n < 8; ++n) {
            int col = n * 16 + r_lane;
            float bias = b1[col];
#pragma unroll
            for (int mt = 0; mt < 2; ++mt) {
                int rbase = m0 + wave * 32 + mt * 16 + quad * 4;
#pragma unroll
                for (int r = 0; r < 4; ++r) {
                    int row = rbase + r;
                    if (row < N_NODES)
                        P1h[(long)row * HID + col] = __float2half(acc[mt][n][r] + bias);
                }
            }
        }
    }

    // stage 2b: P1b = h @ W1b (bf16)
    {
        const __bf16* W1b = Wsw + 32768;
        f32x4 acc[2][8] = {};
#pragma unroll
        for (int ks = 0; ks < 4; ++ks) {
            int kb = ks * 32 + quad * 8;
            bf16x8 bf[8];
#pragma unroll
            for (int n = 0; n < 8; ++n)
                bf[n] = *(const bf16x8*)(W1b + ((ks * 8 + n) * 64 + lane) * 8);
            bf16x8 a0 = *(const bf16x8*)(&At[wave * 32 + r_lane][kb]);
            bf16x8 a1 = *(const bf16x8*)(&At[wave * 32 + 16 + r_lane][kb]);
#pragma unroll
            for (int n = 0; n < 8; ++n) {
                acc[0][n] = __builtin_amdgcn_mfma_f32_16x16x32_bf16(a0, bf[n], acc[0][n], 0, 0, 0);
                acc[1][n] = __builtin_amdgcn_mfma_f32_16x16x32_bf16(a1, bf[n], acc[1][n], 0, 0, 0);
            }
        }
#pragma unroll
        for (int n = 0; n < 8; ++n) {
            int col = n * 16 + r_lane;
#pragma unroll
            for (int mt = 0; mt < 2; ++mt) {
                int rbase = m0 + wave * 32 + mt * 16 + quad * 4;
#pragma unroll
                for (int r = 0; r < 4; ++r) {
                    int row = rbase + r;
                    if (row < N_NODES)
                        P1b[(long)row * HID + col] = (__bf16)acc[mt][n][r];
                }
            }
        }
    }
}

// ---------------------------------------------------------------------------
// 8 relu-accumulates of one P1b row (8 bf16 in uint4) against P1a (f32x8)
// ---------------------------------------------------------------------------
__device__ inline void acc8(float4& rA, float4& rB,
                            const float4 paA, const float4 paB, uint4 q)
{
    float t;
    t = paA.x + __uint_as_float(q.x << 16);         rA.x += t > 0.f ? t : 0.f;
    t = paA.y + __uint_as_float(q.x & 0xffff0000u); rA.y += t > 0.f ? t : 0.f;
    t = paA.z + __uint_as_float(q.y << 16);         rA.z += t > 0.f ? t : 0.f;
    t = paA.w + __uint_as_float(q.y & 0xffff0000u); rA.w += t > 0.f ? t : 0.f;
    t = paB.x + __uint_as_float(q.z << 16);         rB.x += t > 0.f ? t : 0.f;
    t = paB.y + __uint_as_float(q.z & 0xffff0000u); rB.y += t > 0.f ? t : 0.f;
    t = paB.z + __uint_as_float(q.w << 16);         rB.z += t > 0.f ? t : 0.f;
    t = paB.w + __uint_as_float(q.w & 0xffff0000u); rB.w += t > 0.f ? t : 0.f;
}

// ---------------------------------------------------------------------------
// aggnode (R13-proven structure; R14: P1a row loaded as 8xfp16 (uint4) and
// expanded once per row -- conversion amortized over deg~16 edges).
// ---------------------------------------------------------------------------
__global__ __launch_bounds__(512) void aggnode_kernel(
    const __half* __restrict__ P1h, const __bf16* __restrict__ P1b,
    const unsigned int* __restrict__ binbuf, const int* __restrict__ bincnt,
    const int* __restrict__ cursor, const int* __restrict__ ovf_cnt,
    const uint2* __restrict__ ovf, const __bf16* __restrict__ Wsw,
    const float* __restrict__ b2, const float* __restrict__ Wc,
    const float* __restrict__ bc, float* __restrict__ out)
{
    __shared__ __bf16 At[128][136];
    __shared__ unsigned short idx[128][CAP];
    __shared__ int lcur[128];
    __shared__ int degS[128];
    __shared__ unsigned int lovf[128];
    __shared__ int lovf_cnt;
    int tid = threadIdx.x;
    int blk = blockIdx.x;
    int m0 = blk * 128;
    int oc = *ovf_cnt;
    if (oc > OVF_MAX) oc = OVF_MAX;

    // ---- phase 0: scatter bin pairs into LDS buckets ----
    if (tid < 128) lcur[tid] = 0;
    if (tid == 0) lovf_cnt = 0;
    __syncthreads();
    {
        int bin = blk >> 1;
        int n = bincnt[bin];
        if (n > BINCAP) n = BINCAP;
        const unsigned int* src = binbuf + bin * BINCAP;
        for (int i = tid; i < n; i += 512) {
            unsigned int u = src[i];
            int d = (int)(u >> 16);
            if ((d >> 7) == blk) {          // our 128-node half of the bin
                int p = atomicAdd(&lcur[d & 127], 1);
                if (p < CAP) idx[d & 127][p] = (unsigned short)(u & 0xffffu);
                else { int o = atomicAdd(&lovf_cnt, 1);
                       if (o < 128) lovf[o] = u; }
            }
        }
    }
    __syncthreads();
    if (tid < 128) {
        int node = m0 + tid;
        degS[tid] = lcur[tid] + ((node < N_NODES) ? cursor[node] : 0);
    }
    __syncthreads();
    int lc = lovf_cnt;
    if (lc > 128) lc = 128;

    // ---- phase 1: aggregate into At ----
    {
        int team = tid >> 4;        // 0..31
        int tl = tid & 15;          // cols [8tl, 8tl+8)
        for (int g = 0; g < 4; ++g) {
            int r = team * 4 + g;
            int node = m0 + r;
            float4 rA = make_float4(0.f, 0.f, 0.f, 0.f);
            float4 rB = make_float4(0.f, 0.f, 0.f, 0.f);
            if (node < N_NODES) {
                int deg = lcur[r];
                if (deg > CAP) deg = CAP;
                const unsigned short* ip = idx[r];
                uint4 ph = *(const uint4*)(P1h + (long)node * HID + tl * 8);
                float2 c0 = __half22float2(*(const __half2*)&ph.x);
                float2 c1 = __half22float2(*(const __half2*)&ph.y);
                float2 c2 = __half22float2(*(const __half2*)&ph.z);
                float2 c3 = __half22float2(*(const __half2*)&ph.w);
                float4 paA = make_float4(c0.x, c0.y, c1.x, c1.y);
                float4 paB = make_float4(c2.x, c2.y, c3.x, c3.y);
                int j = 0;
                for (; j + 8 <= deg; j += 8) {
                    int s0 = ip[j + 0];
                    int s1 = ip[j + 1];
                    int s2 = ip[j + 2];
                    int s3 = ip[j + 3];
                    int s4 = ip[j + 4];
                    int s5 = ip[j + 5];
                    int s6 = ip[j + 6];
                    int s7 = ip[j + 7];
                    uint4 q0 = *(const uint4*)(P1b + (long)s0 * HID + tl * 8);
                    uint4 q1 = *(const uint4*)(P1b + (long)s1 * HID + tl * 8);
                    uint4 q2 = *(const uint4*)(P1b + (long)s2 * HID + tl * 8);
                    uint4 q3 = *(const uint4*)(P1b + (long)s3 * HID + tl * 8);
                    uint4 q4 = *(const uint4*)(P1b + (long)s4 * HID + tl * 8);
                    uint4 q5 = *(const uint4*)(P1b + (long)s5 * HID + tl * 8);
                    uint4 q6 = *(const uint4*)(P1b + (long)s6 * HID + tl * 8);
                    uint4 q7 = *(const uint4*)(P1b + (long)s7 * HID + tl * 8);
                    acc8(rA, rB, paA, paB, q0);
                    acc8(rA, rB, paA, paB, q1);
                    acc8(rA, rB, paA, paB, q2);
                    acc8(rA, rB, paA, paB, q3);
                    acc8(rA, rB, paA, paB, q4);
                    acc8(rA, rB, paA, paB, q5);
                    acc8(rA, rB, paA, paB, q6);
                    acc8(rA, rB, paA, paB, q7);
                }
                for (; j < deg; ++j) {
                    int s = ip[j];
                    uint4 q = *(const uint4*)(P1b + (long)s * HID + tl * 8);
                    acc8(rA, rB, paA, paB, q);
                }
                for (int t = 0; t < lc; ++t) {   // in-block bucket overflow
                    unsigned int u = lovf[t];
                    if ((int)(u >> 16) == node) {
                        uint4 q = *(const uint4*)(P1b + (long)(u & 0xffffu) * HID + tl * 8);
                        acc8(rA, rB, paA, paB, q);
                    }
                }
                if (oc) {                        // coarse overflow (global)
                    for (int t = 0; t < oc; ++t) {
                        uint2 e = ovf[t];
                        if ((int)e.x == node) {
                            uint4 q = *(const uint4*)(P1b + (long)e.y * HID + tl * 8);
                            acc8(rA, rB, paA, paB, q);
                        }
                    }
                }
            }
            __bf16 vv[8];
            vv[0] = (__bf16)rA.x; vv[1] = (__bf16)rA.y;
            vv[2] = (__bf16)rA.z; vv[3] = (__bf16)rA.w;
            vv[4] = (__bf16)rB.x; vv[5] = (__bf16)rB.y;
            vv[6] = (__bf16)rB.z; vv[7] = (__bf16)rB.w;
            *(uint4*)(&At[r][tl * 8]) = *(uint4*)vv;
        }
    }
    __syncthreads();

    // ---- phase 2: node GEMM, 8 waves x one 16-row m-tile ----
    int wave = tid >> 6, lane = tid & 63;
    int r_lane = lane & 15, quad = lane >> 4;
    const __bf16* W2f = Wsw + 49152;
    f32x4 acc[8] = {};
#pragma unroll
    for (int ks = 0; ks < 4; ++ks) {
        int kb = ks * 32 + quad * 8;
        bf16x8 bf[8];
#pragma unroll
        for (int n = 0; n < 8; ++n)
            bf[n] = *(const bf16x8*)(W2f + ((ks * 8 + n) * 64 + lane) * 8);
        bf16x8 a0 = *(const bf16x8*)(&At[wave * 16 + r_lane][kb]);
#pragma unroll
        for (int n = 0; n < 8; ++n)
            acc[n] = __builtin_amdgcn_mfma_f32_16x16x32_bf16(a0, bf[n], acc[n], 0, 0, 0);
    }

#pragma unroll
    for (int r = 0; r < 4; ++r) {
        int lr = wave * 16 + quad * 4 + r;
        int row = m0 + lr;
        float deg = (float)degS[lr];
        float s0 = 0.f, s1 = 0.f;
#pragma unroll
        for (int n = 0; n < 8; ++n) {
            int col = n * 16 + r_lane;
            float v = acc[n][r] + deg * b2[col];
            v = v > 0.f ? v : 0.f;
            s0 += v * Wc[col * 2 + 0];
            s1 += v * Wc[col * 2 + 1];
        }
#pragma unroll
        for (int off = 1; off < 16; off <<= 1) {
            s0 += __shfl_xor(s0, off);
            s1 += __shfl_xor(s1, off);
        }
        if (r_lane == 0 && row < N_NODES) {
            out[(long)row * 2 + 0] = s0 + bc[0];
            out[(long)row * 2 + 1] = s1 + bc[1];
        }
    }
}

extern "C" void kernel_launch(void* const* d_in, const int* in_sizes, int n_in,
                              void* d_out, int out_size, void* d_ws, size_t ws_size,
                              hipStream_t stream) {
    const float* x    = (const float*)d_in[0];
    const int* eidx   = (const int*)d_in[1];
    const float* W_in = (const float*)d_in[2];
    const float* b_in = (const float*)d_in[3];
    const float* W1   = (const float*)d_in[4];
    const float* b1   = (const float*)d_in[5];
    const float* W2   = (const float*)d_in[6];
    const float* b2   = (const float*)d_in[7];
    const float* Wc   = (const float*)d_in[8];
    const float* bc   = (const float*)d_in[9];
    float* out = (float*)d_out;

    char* ws = (char*)d_ws;
    __half* P1h  = (__half*)(ws + 0);                       // 12,800,000
    __bf16* P1b  = (__bf16*)(ws + 12800000);                // 12,800,000 -> 25,600,000
    int* cursor  = (int*)(ws + 25600000);                   // 50,000*4 = 200,000
    int* bincnt  = cursor + N_NODES;                        // 196*4 (contiguous)
    int* ovf_cnt = cursor + N_NODES + NBIN;                 // 4 (contiguous)
    uint2* ovf   = (uint2*)(ws + 25800800);                 // 65,536 -> 25,866,336
    __bf16* Wsw  = (__bf16*)(ws + 25866368);                // 131,072 -> 25,997,440
    unsigned int* binbuf = (unsigned int*)(ws + 25997440);  // 196*4608*4 = 3,612,672
                                                            // -> end 29,610,112

    prep_kernel<<<256, 256, 0, stream>>>(W_in, W1, W2, Wsw, cursor);
    fused_kernel<<<NCOARSE + NPROJ, 256, 0, stream>>>(
        x, Wsw, b_in, b1, P1h, P1b, eidx, bincnt, binbuf, cursor, ovf_cnt, ovf);
    aggnode_kernel<<<(N_NODES + 127) / 128, 512, 0, stream>>>(
        P1h, P1b, binbuf, bincnt, cursor, ovf_cnt, ovf, Wsw, b2, Wc, bc, out);
}